// Round 1
// baseline (105.458 us; speedup 1.0000x reference)
//
#include <hip/hip_runtime.h>
#include <math.h>

#define DIM 4096
#define H 32
#define D 128
#define SMAX 2048
#define CHUNK 64
#define NCHUNK (SMAX / CHUNK)   // 32
#define PART_STRIDE 130         // m, l, acc[128]

// ---------------- fused Q/K/V matvec: y[row] = dot(W[row,:], x) ----------------
__global__ void matvec_qkv(const float* __restrict__ wq, const float* __restrict__ wk,
                           const float* __restrict__ wv, const float* __restrict__ x,
                           float* __restrict__ y) {
    __shared__ float red[4];
    int row = blockIdx.x;           // 0..3*DIM-1
    const float* w;
    if (row < DIM)            w = wq + (size_t)row * DIM;
    else if (row < 2 * DIM)   w = wk + (size_t)(row - DIM) * DIM;
    else                      w = wv + (size_t)(row - 2 * DIM) * DIM;

    int t = threadIdx.x;            // 256 threads
    float acc = 0.f;
#pragma unroll
    for (int i = 0; i < DIM / (256 * 4); ++i) {
        int idx = (i * 256 + t) * 4;
        const float4 a = *reinterpret_cast<const float4*>(w + idx);
        const float4 b = *reinterpret_cast<const float4*>(x + idx);
        acc = fmaf(a.x, b.x, acc);
        acc = fmaf(a.y, b.y, acc);
        acc = fmaf(a.z, b.z, acc);
        acc = fmaf(a.w, b.w, acc);
    }
#pragma unroll
    for (int off = 32; off; off >>= 1) acc += __shfl_xor(acc, off);
    if ((t & 63) == 0) red[t >> 6] = acc;
    __syncthreads();
    if (t == 0) y[row] = red[0] + red[1] + red[2] + red[3];
}

// ---------------- single matvec: out = W @ v ----------------
__global__ void matvec_o(const float* __restrict__ w_, const float* __restrict__ v,
                         float* __restrict__ y) {
    __shared__ float red[4];
    int row = blockIdx.x;
    const float* w = w_ + (size_t)row * DIM;
    int t = threadIdx.x;
    float acc = 0.f;
#pragma unroll
    for (int i = 0; i < DIM / (256 * 4); ++i) {
        int idx = (i * 256 + t) * 4;
        const float4 a = *reinterpret_cast<const float4*>(w + idx);
        const float4 b = *reinterpret_cast<const float4*>(v + idx);
        acc = fmaf(a.x, b.x, acc);
        acc = fmaf(a.y, b.y, acc);
        acc = fmaf(a.z, b.z, acc);
        acc = fmaf(a.w, b.w, acc);
    }
#pragma unroll
    for (int off = 32; off; off >>= 1) acc += __shfl_xor(acc, off);
    if ((t & 63) == 0) red[t >> 6] = acc;
    __syncthreads();
    if (t == 0) y[row] = red[0] + red[1] + red[2] + red[3];
}

// ---------------- RoPE in-place on xq, xk ----------------
__global__ void rope_qk(float* __restrict__ xq, float* __restrict__ xk,
                        const int* __restrict__ pos_p) {
    int tid = blockIdx.x * blockDim.x + threadIdx.x;   // 0..4095 (2 mats * 32 heads * 64 pairs)
    if (tid >= 2 * H * (D / 2)) return;
    int pos = *pos_p;
    float* base = (tid < H * (D / 2)) ? xq : xk;
    int r = tid & (H * (D / 2) - 1);
    int h = r >> 6;
    int j = r & 63;
    float theta = powf(10000.0f, -(float)(2 * j) / (float)D);
    float ang = (float)pos * theta;
    float s, c;
    sincosf(ang, &s, &c);
    float* v = base + h * D + 2 * j;
    float v0 = v[0], v1 = v[1];
    v[0] = v0 * c - v1 * s;
    v[1] = v0 * s + v1 * c;
}

// ---------------- flash-decode partials: one wave per (head, chunk) ----------------
__global__ void attn_partial(const float* __restrict__ cache_k, const float* __restrict__ cache_v,
                             const float* __restrict__ xq, const float* __restrict__ xk,
                             const float* __restrict__ xv, const int* __restrict__ pos_p,
                             float* __restrict__ partials) {
    int h = blockIdx.x;
    int c = blockIdx.y;
    int lane = threadIdx.x;          // 64 lanes, each owns dims 2*lane, 2*lane+1
    int pos = *pos_p;
    int p0 = c * CHUNK;
    int p1 = min(p0 + CHUNK, pos + 1);
    float* pp = partials + (size_t)(h * NCHUNK + c) * PART_STRIDE;

    if (p0 > pos) {   // inactive chunk: write identity partial
        if (lane == 0) { pp[0] = -INFINITY; pp[1] = 0.f; }
        reinterpret_cast<float2*>(pp + 2)[lane] = make_float2(0.f, 0.f);
        return;
    }

    float2 q = reinterpret_cast<const float2*>(xq + h * D)[lane];
    float m = -INFINITY, l = 0.f, a0 = 0.f, a1 = 0.f;

    for (int p = p0; p < p1; ++p) {
        const float* kp = (p == pos) ? (xk + h * D)
                                     : (cache_k + ((size_t)p * H + h) * D);
        float2 k = reinterpret_cast<const float2*>(kp)[lane];
        float d = q.x * k.x + q.y * k.y;
#pragma unroll
        for (int off = 32; off; off >>= 1) d += __shfl_xor(d, off);
        float s = d * 0.08838834764831845f;   // 1/sqrt(128)
        float mn = fmaxf(m, s);
        float corr = __expf(m - mn);          // exp(-inf)=0 on first iter
        float wgt = __expf(s - mn);
        const float* vp = (p == pos) ? (xv + h * D)
                                     : (cache_v + ((size_t)p * H + h) * D);
        float2 v = reinterpret_cast<const float2*>(vp)[lane];
        l = l * corr + wgt;
        a0 = a0 * corr + wgt * v.x;
        a1 = a1 * corr + wgt * v.y;
        m = mn;
    }
    if (lane == 0) { pp[0] = m; pp[1] = l; }
    reinterpret_cast<float2*>(pp + 2)[lane] = make_float2(a0, a1);
}

// ---------------- combine partials per head ----------------
__global__ void attn_combine(const float* __restrict__ partials, float* __restrict__ out_attn) {
    int h = blockIdx.x;
    int lane = threadIdx.x;          // 64 lanes, dims 2*lane, 2*lane+1
    float m = -INFINITY;
    for (int c = 0; c < NCHUNK; ++c)
        m = fmaxf(m, partials[(size_t)(h * NCHUNK + c) * PART_STRIDE]);
    float L = 0.f, a0 = 0.f, a1 = 0.f;
    for (int c = 0; c < NCHUNK; ++c) {
        const float* pp = partials + (size_t)(h * NCHUNK + c) * PART_STRIDE;
        float w = __expf(pp[0] - m);      // exp(-inf - m) = 0 for empty chunks
        L += pp[1] * w;
        float2 a = reinterpret_cast<const float2*>(pp + 2)[lane];
        a0 += w * a.x;
        a1 += w * a.y;
    }
    float inv = 1.f / L;
    out_attn[h * D + 2 * lane]     = a0 * inv;
    out_attn[h * D + 2 * lane + 1] = a1 * inv;
}

extern "C" void kernel_launch(void* const* d_in, const int* in_sizes, int n_in,
                              void* d_out, int out_size, void* d_ws, size_t ws_size,
                              hipStream_t stream) {
    const float* x       = (const float*)d_in[0];
    const float* wq      = (const float*)d_in[1];
    const float* wk      = (const float*)d_in[2];
    const float* wv      = (const float*)d_in[3];
    const float* wo      = (const float*)d_in[4];
    const float* cache_k = (const float*)d_in[5];
    const float* cache_v = (const float*)d_in[6];
    const int*   pos     = (const int*)d_in[7];

    float* ws       = (float*)d_ws;
    float* xq       = ws;                 // 4096
    float* xk       = ws + DIM;           // 4096
    float* xv       = ws + 2 * DIM;       // 4096
    float* partials = ws + 3 * DIM;       // 32*32*130
    float* out_attn = partials + H * NCHUNK * PART_STRIDE;  // 4096
    float* out      = (float*)d_out;

    matvec_qkv<<<3 * DIM, 256, 0, stream>>>(wq, wk, wv, x, ws);
    rope_qk<<<16, 256, 0, stream>>>(xq, xk, pos);
    attn_partial<<<dim3(H, NCHUNK), 64, 0, stream>>>(cache_k, cache_v, xq, xk, xv, pos, partials);
    attn_combine<<<H, 64, 0, stream>>>(partials, out_attn);
    matvec_o<<<DIM, 256, 0, stream>>>(wo, out_attn, out);
}

// Round 2
// 82.284 us; speedup vs baseline: 1.2816x; 1.2816x over previous
//
#include <hip/hip_runtime.h>
#include <math.h>

#define DIM 4096
#define H 32
#define D 128
#define SMAX 2048
#define CHUNK 32
#define NCHUNK (SMAX / CHUNK)   // 64
#define PART_STRIDE 130         // m, l, acc[128]

// ---------------- fused Q/K/V matvec: wave-per-row ----------------
// grid = 3*DIM/4 blocks of 256 (4 waves); wave w of block handles row blockIdx.x*4+w
__global__ void matvec_qkv(const float* __restrict__ wq, const float* __restrict__ wk,
                           const float* __restrict__ wv, const float* __restrict__ x,
                           float* __restrict__ y) {
    int row  = blockIdx.x * 4 + (threadIdx.x >> 6);
    int lane = threadIdx.x & 63;
    const float* w;
    if (row < DIM)            w = wq + (size_t)row * DIM;
    else if (row < 2 * DIM)   w = wk + (size_t)(row - DIM) * DIM;
    else                      w = wv + (size_t)(row - 2 * DIM) * DIM;

    float a0 = 0.f, a1 = 0.f, a2 = 0.f, a3 = 0.f;
#pragma unroll
    for (int i = 0; i < DIM / (64 * 4); ++i) {      // 16 iterations
        int idx = (i * 64 + lane) * 4;
        const float4 a = *reinterpret_cast<const float4*>(w + idx);
        const float4 b = *reinterpret_cast<const float4*>(x + idx);
        a0 = fmaf(a.x, b.x, a0);
        a1 = fmaf(a.y, b.y, a1);
        a2 = fmaf(a.z, b.z, a2);
        a3 = fmaf(a.w, b.w, a3);
    }
    float acc = (a0 + a1) + (a2 + a3);
#pragma unroll
    for (int off = 32; off; off >>= 1) acc += __shfl_xor(acc, off);
    if (lane == 0) y[row] = acc;
}

// ---------------- single matvec: out = W @ v (wave-per-row) ----------------
__global__ void matvec_o(const float* __restrict__ w_, const float* __restrict__ v,
                         float* __restrict__ y) {
    int row  = blockIdx.x * 4 + (threadIdx.x >> 6);
    int lane = threadIdx.x & 63;
    const float* w = w_ + (size_t)row * DIM;
    float a0 = 0.f, a1 = 0.f, a2 = 0.f, a3 = 0.f;
#pragma unroll
    for (int i = 0; i < DIM / (64 * 4); ++i) {
        int idx = (i * 64 + lane) * 4;
        const float4 a = *reinterpret_cast<const float4*>(w + idx);
        const float4 b = *reinterpret_cast<const float4*>(v + idx);
        a0 = fmaf(a.x, b.x, a0);
        a1 = fmaf(a.y, b.y, a1);
        a2 = fmaf(a.z, b.z, a2);
        a3 = fmaf(a.w, b.w, a3);
    }
    float acc = (a0 + a1) + (a2 + a3);
#pragma unroll
    for (int off = 32; off; off >>= 1) acc += __shfl_xor(acc, off);
    if (lane == 0) y[row] = acc;
}

// ---------------- RoPE in-place on xq, xk ----------------
__global__ void rope_qk(float* __restrict__ xq, float* __restrict__ xk,
                        const int* __restrict__ pos_p) {
    int tid = blockIdx.x * blockDim.x + threadIdx.x;   // 0..4095
    if (tid >= 2 * H * (D / 2)) return;
    int pos = *pos_p;
    float* base = (tid < H * (D / 2)) ? xq : xk;
    int r = tid & (H * (D / 2) - 1);
    int h = r >> 6;
    int j = r & 63;
    float theta = powf(10000.0f, -(float)(2 * j) / (float)D);
    float ang = (float)pos * theta;
    float s, c;
    sincosf(ang, &s, &c);
    float* v = base + h * D + 2 * j;
    float v0 = v[0], v1 = v[1];
    v[0] = v0 * c - v1 * s;
    v[1] = v0 * s + v1 * c;
}

// ---------------- flash-decode partials ----------------
// one wave per (head, chunk of 32 positions); 4x 16-lane groups, each group
// processes every 4th position with 8 dims/lane; block-combines groups in LDS.
__global__ void attn_partial(const float* __restrict__ cache_k, const float* __restrict__ cache_v,
                             const float* __restrict__ xq, const float* __restrict__ xk,
                             const float* __restrict__ xv, const int* __restrict__ pos_p,
                             float* __restrict__ partials) {
    __shared__ float lds_m[4], lds_l[4];
    __shared__ float lds_acc[4][128];
    int h = blockIdx.x;
    int c = blockIdx.y;
    int lane = threadIdx.x;          // 64
    int g  = lane >> 4;              // group 0..3
    int gl = lane & 15;              // lane-in-group; owns dims gl*8 .. gl*8+7
    int pos = *pos_p;
    int base = c * CHUNK;
    int p1 = min(base + CHUNK, pos + 1);
    float* pp = partials + (size_t)(h * NCHUNK + c) * PART_STRIDE;

    if (base > pos) {   // fully inactive chunk: identity partial
        if (lane == 0) { pp[0] = -INFINITY; pp[1] = 0.f; }
        reinterpret_cast<float2*>(pp + 2)[lane] = make_float2(0.f, 0.f);
        return;
    }

    const float4* qv = reinterpret_cast<const float4*>(xq + h * D + gl * 8);
    const float4 q0 = qv[0], q1 = qv[1];

    float m = -INFINITY, l = 0.f;
    float4 acc0 = make_float4(0.f, 0.f, 0.f, 0.f);
    float4 acc1 = make_float4(0.f, 0.f, 0.f, 0.f);

    for (int p = base + g; p < p1; p += 4) {
        const float* kp = (p == pos) ? (xk + h * D)
                                     : (cache_k + ((size_t)p * H + h) * D);
        const float4* kv4 = reinterpret_cast<const float4*>(kp + gl * 8);
        float4 k0 = kv4[0], k1 = kv4[1];
        float d = q0.x * k0.x + q0.y * k0.y + q0.z * k0.z + q0.w * k0.w
                + q1.x * k1.x + q1.y * k1.y + q1.z * k1.z + q1.w * k1.w;
        d += __shfl_xor(d, 1);
        d += __shfl_xor(d, 2);
        d += __shfl_xor(d, 4);
        d += __shfl_xor(d, 8);       // all 16 lanes of the group hold the dot
        float s = d * 0.08838834764831845f;   // 1/sqrt(128)
        float mn = fmaxf(m, s);
        float corr = __expf(m - mn);          // exp(-inf)=0 on first iter
        float wgt  = __expf(s - mn);
        const float* vp = (p == pos) ? (xv + h * D)
                                     : (cache_v + ((size_t)p * H + h) * D);
        const float4* vv4 = reinterpret_cast<const float4*>(vp + gl * 8);
        float4 v0 = vv4[0], v1 = vv4[1];
        l = l * corr + wgt;
        acc0.x = fmaf(wgt, v0.x, acc0.x * corr);
        acc0.y = fmaf(wgt, v0.y, acc0.y * corr);
        acc0.z = fmaf(wgt, v0.z, acc0.z * corr);
        acc0.w = fmaf(wgt, v0.w, acc0.w * corr);
        acc1.x = fmaf(wgt, v1.x, acc1.x * corr);
        acc1.y = fmaf(wgt, v1.y, acc1.y * corr);
        acc1.z = fmaf(wgt, v1.z, acc1.z * corr);
        acc1.w = fmaf(wgt, v1.w, acc1.w * corr);
        m = mn;
    }

    // combine the 4 groups inside the block
    if (gl == 0) { lds_m[g] = m; lds_l[g] = l; }
    *reinterpret_cast<float4*>(&lds_acc[g][gl * 8])     = acc0;
    *reinterpret_cast<float4*>(&lds_acc[g][gl * 8 + 4]) = acc1;
    __syncthreads();
    float M = fmaxf(fmaxf(lds_m[0], lds_m[1]), fmaxf(lds_m[2], lds_m[3]));
    // chunk is active => group 0 non-empty => M finite
    float w0 = __expf(lds_m[0] - M);
    float w1 = __expf(lds_m[1] - M);
    float w2 = __expf(lds_m[2] - M);
    float w3 = __expf(lds_m[3] - M);
    float L  = w0 * lds_l[0] + w1 * lds_l[1] + w2 * lds_l[2] + w3 * lds_l[3];
    int d0 = 2 * lane;
    float s0 = w0 * lds_acc[0][d0]     + w1 * lds_acc[1][d0]
             + w2 * lds_acc[2][d0]     + w3 * lds_acc[3][d0];
    float s1 = w0 * lds_acc[0][d0 + 1] + w1 * lds_acc[1][d0 + 1]
             + w2 * lds_acc[2][d0 + 1] + w3 * lds_acc[3][d0 + 1];
    if (lane == 0) { pp[0] = M; pp[1] = L; }
    reinterpret_cast<float2*>(pp + 2)[lane] = make_float2(s0, s1);
}

// ---------------- combine partials per head ----------------
__global__ void attn_combine(const float* __restrict__ partials, float* __restrict__ out_attn) {
    int h = blockIdx.x;
    int lane = threadIdx.x;          // 64 lanes, dims 2*lane, 2*lane+1
    float m = -INFINITY;
    for (int c = 0; c < NCHUNK; ++c)
        m = fmaxf(m, partials[(size_t)(h * NCHUNK + c) * PART_STRIDE]);
    float L = 0.f, a0 = 0.f, a1 = 0.f;
    for (int c = 0; c < NCHUNK; ++c) {
        const float* pp = partials + (size_t)(h * NCHUNK + c) * PART_STRIDE;
        float w = __expf(pp[0] - m);      // exp(-inf - m) = 0 for empty chunks
        L += pp[1] * w;
        float2 a = reinterpret_cast<const float2*>(pp + 2)[lane];
        a0 += w * a.x;
        a1 += w * a.y;
    }
    float inv = 1.f / L;
    out_attn[h * D + 2 * lane]     = a0 * inv;
    out_attn[h * D + 2 * lane + 1] = a1 * inv;
}

extern "C" void kernel_launch(void* const* d_in, const int* in_sizes, int n_in,
                              void* d_out, int out_size, void* d_ws, size_t ws_size,
                              hipStream_t stream) {
    const float* x       = (const float*)d_in[0];
    const float* wq      = (const float*)d_in[1];
    const float* wk      = (const float*)d_in[2];
    const float* wv      = (const float*)d_in[3];
    const float* wo      = (const float*)d_in[4];
    const float* cache_k = (const float*)d_in[5];
    const float* cache_v = (const float*)d_in[6];
    const int*   pos     = (const int*)d_in[7];

    float* ws       = (float*)d_ws;
    float* xq       = ws;                 // 4096
    float* xk       = ws + DIM;           // 4096
    float* xv       = ws + 2 * DIM;       // 4096
    float* partials = ws + 3 * DIM;       // 32*64*130
    float* out_attn = partials + H * NCHUNK * PART_STRIDE;  // 4096
    float* out      = (float*)d_out;

    matvec_qkv<<<3 * DIM / 4, 256, 0, stream>>>(wq, wk, wv, x, ws);
    rope_qk<<<16, 256, 0, stream>>>(xq, xk, pos);
    attn_partial<<<dim3(H, NCHUNK), 64, 0, stream>>>(cache_k, cache_v, xq, xk, xv, pos, partials);
    attn_combine<<<H, 64, 0, stream>>>(partials, out_attn);
    matvec_o<<<DIM / 4, 256, 0, stream>>>(wo, out_attn, out);
}

// Round 3
// 81.801 us; speedup vs baseline: 1.2892x; 1.0059x over previous
//
#include <hip/hip_runtime.h>
#include <math.h>

#define DIM 4096
#define H 32
#define D 128
#define SMAX 2048
#define CHUNK 32
#define NCHUNK (SMAX / CHUNK)   // 64
#define PART_STRIDE 130         // m, l, acc[128]

// ---------------- fused Q/K/V matvec ----------------
// 4 waves/block, wave-per-row, x staged in LDS, all 16 weight float4 loads
// issued back-to-back into a register array before use (16 loads in flight).
__global__ void __launch_bounds__(256) matvec_qkv(
        const float* __restrict__ wq, const float* __restrict__ wk,
        const float* __restrict__ wv, const float* __restrict__ x,
        float* __restrict__ y) {
    __shared__ float xs[DIM];          // 16 KB
    int t    = threadIdx.x;
    int lane = t & 63;
    int row  = blockIdx.x * 4 + (t >> 6);

    // issue x loads first (4 oldest vmcnt entries -> ds_write waits only on these)
    float4 xr[4];
#pragma unroll
    for (int i = 0; i < 4; ++i)
        xr[i] = *reinterpret_cast<const float4*>(x + (i * 256 + t) * 4);

    const float* w;
    if (row < DIM)            w = wq + (size_t)row * DIM;
    else if (row < 2 * DIM)   w = wk + (size_t)(row - DIM) * DIM;
    else                      w = wv + (size_t)(row - 2 * DIM) * DIM;

    // 16 weight loads in flight per lane
    float4 a[16];
#pragma unroll
    for (int i = 0; i < 16; ++i)
        a[i] = *reinterpret_cast<const float4*>(w + (i * 64 + lane) * 4);

#pragma unroll
    for (int i = 0; i < 4; ++i)
        *reinterpret_cast<float4*>(&xs[(i * 256 + t) * 4]) = xr[i];
    __syncthreads();

    float s0 = 0.f, s1 = 0.f, s2 = 0.f, s3 = 0.f;
#pragma unroll
    for (int i = 0; i < 16; ++i) {
        const float4 b = *reinterpret_cast<const float4*>(&xs[(i * 64 + lane) * 4]);
        s0 = fmaf(a[i].x, b.x, s0);
        s1 = fmaf(a[i].y, b.y, s1);
        s2 = fmaf(a[i].z, b.z, s2);
        s3 = fmaf(a[i].w, b.w, s3);
    }
    float acc = (s0 + s1) + (s2 + s3);
#pragma unroll
    for (int off = 32; off; off >>= 1) acc += __shfl_xor(acc, off);
    if (lane == 0) y[row] = acc;
}

// ---------------- single matvec: out = W @ v ----------------
__global__ void __launch_bounds__(256) matvec_o(
        const float* __restrict__ w_, const float* __restrict__ v,
        float* __restrict__ y) {
    __shared__ float xs[DIM];
    int t    = threadIdx.x;
    int lane = t & 63;
    int row  = blockIdx.x * 4 + (t >> 6);

    float4 xr[4];
#pragma unroll
    for (int i = 0; i < 4; ++i)
        xr[i] = *reinterpret_cast<const float4*>(v + (i * 256 + t) * 4);

    const float* w = w_ + (size_t)row * DIM;
    float4 a[16];
#pragma unroll
    for (int i = 0; i < 16; ++i)
        a[i] = *reinterpret_cast<const float4*>(w + (i * 64 + lane) * 4);

#pragma unroll
    for (int i = 0; i < 4; ++i)
        *reinterpret_cast<float4*>(&xs[(i * 256 + t) * 4]) = xr[i];
    __syncthreads();

    float s0 = 0.f, s1 = 0.f, s2 = 0.f, s3 = 0.f;
#pragma unroll
    for (int i = 0; i < 16; ++i) {
        const float4 b = *reinterpret_cast<const float4*>(&xs[(i * 64 + lane) * 4]);
        s0 = fmaf(a[i].x, b.x, s0);
        s1 = fmaf(a[i].y, b.y, s1);
        s2 = fmaf(a[i].z, b.z, s2);
        s3 = fmaf(a[i].w, b.w, s3);
    }
    float acc = (s0 + s1) + (s2 + s3);
#pragma unroll
    for (int off = 32; off; off >>= 1) acc += __shfl_xor(acc, off);
    if (lane == 0) y[row] = acc;
}

// ---------------- RoPE in-place on xq, xk ----------------
__global__ void rope_qk(float* __restrict__ xq, float* __restrict__ xk,
                        const int* __restrict__ pos_p) {
    int tid = blockIdx.x * blockDim.x + threadIdx.x;   // 0..4095
    if (tid >= 2 * H * (D / 2)) return;
    int pos = *pos_p;
    float* base = (tid < H * (D / 2)) ? xq : xk;
    int r = tid & (H * (D / 2) - 1);
    int h = r >> 6;
    int j = r & 63;
    float theta = powf(10000.0f, -(float)(2 * j) / (float)D);
    float ang = (float)pos * theta;
    float s, c;
    sincosf(ang, &s, &c);
    float* v = base + h * D + 2 * j;
    float v0 = v[0], v1 = v[1];
    v[0] = v0 * c - v1 * s;
    v[1] = v0 * s + v1 * c;
}

// ---------------- flash-decode partials ----------------
// one wave per (head, chunk of 32 positions); 4x 16-lane groups, each group
// processes every 4th position with 8 dims/lane; block-combines groups in LDS.
__global__ void attn_partial(const float* __restrict__ cache_k, const float* __restrict__ cache_v,
                             const float* __restrict__ xq, const float* __restrict__ xk,
                             const float* __restrict__ xv, const int* __restrict__ pos_p,
                             float* __restrict__ partials) {
    __shared__ float lds_m[4], lds_l[4];
    __shared__ float lds_acc[4][128];
    int h = blockIdx.x;
    int c = blockIdx.y;
    int lane = threadIdx.x;          // 64
    int g  = lane >> 4;              // group 0..3
    int gl = lane & 15;              // lane-in-group; owns dims gl*8 .. gl*8+7
    int pos = *pos_p;
    int base = c * CHUNK;
    int p1 = min(base + CHUNK, pos + 1);
    float* pp = partials + (size_t)(h * NCHUNK + c) * PART_STRIDE;

    if (base > pos) {   // fully inactive chunk: identity partial
        if (lane == 0) { pp[0] = -INFINITY; pp[1] = 0.f; }
        reinterpret_cast<float2*>(pp + 2)[lane] = make_float2(0.f, 0.f);
        return;
    }

    const float4* qv = reinterpret_cast<const float4*>(xq + h * D + gl * 8);
    const float4 q0 = qv[0], q1 = qv[1];

    float m = -INFINITY, l = 0.f;
    float4 acc0 = make_float4(0.f, 0.f, 0.f, 0.f);
    float4 acc1 = make_float4(0.f, 0.f, 0.f, 0.f);

    for (int p = base + g; p < p1; p += 4) {
        const float* kp = (p == pos) ? (xk + h * D)
                                     : (cache_k + ((size_t)p * H + h) * D);
        const float4* kv4 = reinterpret_cast<const float4*>(kp + gl * 8);
        float4 k0 = kv4[0], k1 = kv4[1];
        float d = q0.x * k0.x + q0.y * k0.y + q0.z * k0.z + q0.w * k0.w
                + q1.x * k1.x + q1.y * k1.y + q1.z * k1.z + q1.w * k1.w;
        d += __shfl_xor(d, 1);
        d += __shfl_xor(d, 2);
        d += __shfl_xor(d, 4);
        d += __shfl_xor(d, 8);       // all 16 lanes of the group hold the dot
        float s = d * 0.08838834764831845f;   // 1/sqrt(128)
        float mn = fmaxf(m, s);
        float corr = __expf(m - mn);          // exp(-inf)=0 on first iter
        float wgt  = __expf(s - mn);
        const float* vp = (p == pos) ? (xv + h * D)
                                     : (cache_v + ((size_t)p * H + h) * D);
        const float4* vv4 = reinterpret_cast<const float4*>(vp + gl * 8);
        float4 v0 = vv4[0], v1 = vv4[1];
        l = l * corr + wgt;
        acc0.x = fmaf(wgt, v0.x, acc0.x * corr);
        acc0.y = fmaf(wgt, v0.y, acc0.y * corr);
        acc0.z = fmaf(wgt, v0.z, acc0.z * corr);
        acc0.w = fmaf(wgt, v0.w, acc0.w * corr);
        acc1.x = fmaf(wgt, v1.x, acc1.x * corr);
        acc1.y = fmaf(wgt, v1.y, acc1.y * corr);
        acc1.z = fmaf(wgt, v1.z, acc1.z * corr);
        acc1.w = fmaf(wgt, v1.w, acc1.w * corr);
        m = mn;
    }

    // combine the 4 groups inside the block
    if (gl == 0) { lds_m[g] = m; lds_l[g] = l; }
    *reinterpret_cast<float4*>(&lds_acc[g][gl * 8])     = acc0;
    *reinterpret_cast<float4*>(&lds_acc[g][gl * 8 + 4]) = acc1;
    __syncthreads();
    float M = fmaxf(fmaxf(lds_m[0], lds_m[1]), fmaxf(lds_m[2], lds_m[3]));
    // chunk is active => group 0 non-empty => M finite
    float w0 = __expf(lds_m[0] - M);
    float w1 = __expf(lds_m[1] - M);
    float w2 = __expf(lds_m[2] - M);
    float w3 = __expf(lds_m[3] - M);
    float L  = w0 * lds_l[0] + w1 * lds_l[1] + w2 * lds_l[2] + w3 * lds_l[3];
    int d0 = 2 * lane;
    float s0 = w0 * lds_acc[0][d0]     + w1 * lds_acc[1][d0]
             + w2 * lds_acc[2][d0]     + w3 * lds_acc[3][d0];
    float s1 = w0 * lds_acc[0][d0 + 1] + w1 * lds_acc[1][d0 + 1]
             + w2 * lds_acc[2][d0 + 1] + w3 * lds_acc[3][d0 + 1];
    if (lane == 0) { pp[0] = M; pp[1] = L; }
    reinterpret_cast<float2*>(pp + 2)[lane] = make_float2(s0, s1);
}

// ---------------- combine partials per head ----------------
__global__ void attn_combine(const float* __restrict__ partials, float* __restrict__ out_attn) {
    int h = blockIdx.x;
    int lane = threadIdx.x;          // 64 lanes, dims 2*lane, 2*lane+1
    float m = -INFINITY;
    for (int c = 0; c < NCHUNK; ++c)
        m = fmaxf(m, partials[(size_t)(h * NCHUNK + c) * PART_STRIDE]);
    float L = 0.f, a0 = 0.f, a1 = 0.f;
    for (int c = 0; c < NCHUNK; ++c) {
        const float* pp = partials + (size_t)(h * NCHUNK + c) * PART_STRIDE;
        float w = __expf(pp[0] - m);      // exp(-inf - m) = 0 for empty chunks
        L += pp[1] * w;
        float2 a = reinterpret_cast<const float2*>(pp + 2)[lane];
        a0 += w * a.x;
        a1 += w * a.y;
    }
    float inv = 1.f / L;
    out_attn[h * D + 2 * lane]     = a0 * inv;
    out_attn[h * D + 2 * lane + 1] = a1 * inv;
}

extern "C" void kernel_launch(void* const* d_in, const int* in_sizes, int n_in,
                              void* d_out, int out_size, void* d_ws, size_t ws_size,
                              hipStream_t stream) {
    const float* x       = (const float*)d_in[0];
    const float* wq      = (const float*)d_in[1];
    const float* wk      = (const float*)d_in[2];
    const float* wv      = (const float*)d_in[3];
    const float* wo      = (const float*)d_in[4];
    const float* cache_k = (const float*)d_in[5];
    const float* cache_v = (const float*)d_in[6];
    const int*   pos     = (const int*)d_in[7];

    float* ws       = (float*)d_ws;
    float* xq       = ws;                 // 4096
    float* xk       = ws + DIM;           // 4096
    float* xv       = ws + 2 * DIM;       // 4096
    float* partials = ws + 3 * DIM;       // 32*64*130
    float* out_attn = partials + H * NCHUNK * PART_STRIDE;  // 4096
    float* out      = (float*)d_out;

    matvec_qkv<<<3 * DIM / 4, 256, 0, stream>>>(wq, wk, wv, x, ws);
    rope_qk<<<16, 256, 0, stream>>>(xq, xk, pos);
    attn_partial<<<dim3(H, NCHUNK), 64, 0, stream>>>(cache_k, cache_v, xq, xk, xv, pos, partials);
    attn_combine<<<H, 64, 0, stream>>>(partials, out_attn);
    matvec_o<<<DIM / 4, 256, 0, stream>>>(wo, out_attn, out);
}

// Round 4
// 81.088 us; speedup vs baseline: 1.3005x; 1.0088x over previous
//
#include <hip/hip_runtime.h>
#include <math.h>

#define DIM 4096
#define H 32
#define D 128
#define SMAX 2048
#define CHUNK 32
#define NCHUNK (SMAX / CHUNK)   // 64
#define PART_STRIDE 130         // m, l, acc[128]

typedef float v4f __attribute__((ext_vector_type(4)));

__device__ inline v4f ntload4(const float* p) {
    return __builtin_nontemporal_load(reinterpret_cast<const v4f*>(p));
}

// ---------------- fused Q/K/V matvec ----------------
// wave-per-row. All 16 x-float4s + 16 nontemporal w-float4s issued into
// registers BEFORE any use; sched_barrier(0) pins the schedule so the
// compiler cannot sink the loads (R3 lesson: it re-pipelines at depth 2).
__global__ void __launch_bounds__(256) matvec_qkv(
        const float* __restrict__ wq, const float* __restrict__ wk,
        const float* __restrict__ wv, const float* __restrict__ x,
        float* __restrict__ y) {
    int t    = threadIdx.x;
    int lane = t & 63;
    int row  = blockIdx.x * 4 + (t >> 6);
    const float* w;
    if (row < DIM)            w = wq + (size_t)row * DIM;
    else if (row < 2 * DIM)   w = wk + (size_t)(row - DIM) * DIM;
    else                      w = wv + (size_t)(row - 2 * DIM) * DIM;

    const int off = lane * 4;   // float offset of this lane's first element

    v4f xv[16];
#pragma unroll
    for (int i = 0; i < 16; ++i)
        xv[i] = *reinterpret_cast<const v4f*>(x + i * 256 + off);
    v4f a[16];
#pragma unroll
    for (int i = 0; i < 16; ++i)
        a[i] = ntload4(w + i * 256 + off);
    __builtin_amdgcn_sched_barrier(0);   // nothing crosses: 32 loads in flight

    float s0 = 0.f, s1 = 0.f, s2 = 0.f, s3 = 0.f;
#pragma unroll
    for (int i = 0; i < 16; ++i) {
        s0 = fmaf(a[i].x, xv[i].x, s0);
        s1 = fmaf(a[i].y, xv[i].y, s1);
        s2 = fmaf(a[i].z, xv[i].z, s2);
        s3 = fmaf(a[i].w, xv[i].w, s3);
    }
    float acc = (s0 + s1) + (s2 + s3);
#pragma unroll
    for (int o = 32; o; o >>= 1) acc += __shfl_xor(acc, o);
    if (lane == 0) y[row] = acc;
}

// ---------------- single matvec: out = W @ v ----------------
__global__ void __launch_bounds__(256) matvec_o(
        const float* __restrict__ w_, const float* __restrict__ v,
        float* __restrict__ y) {
    int t    = threadIdx.x;
    int lane = t & 63;
    int row  = blockIdx.x * 4 + (t >> 6);
    const float* w = w_ + (size_t)row * DIM;
    const int off = lane * 4;

    v4f xv[16];
#pragma unroll
    for (int i = 0; i < 16; ++i)
        xv[i] = *reinterpret_cast<const v4f*>(v + i * 256 + off);
    v4f a[16];
#pragma unroll
    for (int i = 0; i < 16; ++i)
        a[i] = ntload4(w + i * 256 + off);
    __builtin_amdgcn_sched_barrier(0);

    float s0 = 0.f, s1 = 0.f, s2 = 0.f, s3 = 0.f;
#pragma unroll
    for (int i = 0; i < 16; ++i) {
        s0 = fmaf(a[i].x, xv[i].x, s0);
        s1 = fmaf(a[i].y, xv[i].y, s1);
        s2 = fmaf(a[i].z, xv[i].z, s2);
        s3 = fmaf(a[i].w, xv[i].w, s3);
    }
    float acc = (s0 + s1) + (s2 + s3);
#pragma unroll
    for (int o = 32; o; o >>= 1) acc += __shfl_xor(acc, o);
    if (lane == 0) y[row] = acc;
}

// ---------------- RoPE in-place on xq, xk ----------------
__global__ void rope_qk(float* __restrict__ xq, float* __restrict__ xk,
                        const int* __restrict__ pos_p) {
    int tid = blockIdx.x * blockDim.x + threadIdx.x;   // 0..4095
    if (tid >= 2 * H * (D / 2)) return;
    int pos = *pos_p;
    float* base = (tid < H * (D / 2)) ? xq : xk;
    int r = tid & (H * (D / 2) - 1);
    int h = r >> 6;
    int j = r & 63;
    float theta = powf(10000.0f, -(float)(2 * j) / (float)D);
    float ang = (float)pos * theta;
    float s, c;
    sincosf(ang, &s, &c);
    float* v = base + h * D + 2 * j;
    float v0 = v[0], v1 = v[1];
    v[0] = v0 * c - v1 * s;
    v[1] = v0 * s + v1 * c;
}

// ---------------- flash-decode partials ----------------
__global__ void attn_partial(const float* __restrict__ cache_k, const float* __restrict__ cache_v,
                             const float* __restrict__ xq, const float* __restrict__ xk,
                             const float* __restrict__ xv, const int* __restrict__ pos_p,
                             float* __restrict__ partials) {
    __shared__ float lds_m[4], lds_l[4];
    __shared__ float lds_acc[4][128];
    int h = blockIdx.x;
    int c = blockIdx.y;
    int lane = threadIdx.x;          // 64
    int g  = lane >> 4;              // group 0..3
    int gl = lane & 15;              // lane-in-group; owns dims gl*8 .. gl*8+7
    int pos = *pos_p;
    int base = c * CHUNK;
    int p1 = min(base + CHUNK, pos + 1);
    float* pp = partials + (size_t)(h * NCHUNK + c) * PART_STRIDE;

    if (base > pos) {   // fully inactive chunk: identity partial
        if (lane == 0) { pp[0] = -INFINITY; pp[1] = 0.f; }
        reinterpret_cast<float2*>(pp + 2)[lane] = make_float2(0.f, 0.f);
        return;
    }

    const float4* qv = reinterpret_cast<const float4*>(xq + h * D + gl * 8);
    const float4 q0 = qv[0], q1 = qv[1];

    float m = -INFINITY, l = 0.f;
    float4 acc0 = make_float4(0.f, 0.f, 0.f, 0.f);
    float4 acc1 = make_float4(0.f, 0.f, 0.f, 0.f);

    for (int p = base + g; p < p1; p += 4) {
        const float* kp = (p == pos) ? (xk + h * D)
                                     : (cache_k + ((size_t)p * H + h) * D);
        const float4* kv4 = reinterpret_cast<const float4*>(kp + gl * 8);
        float4 k0 = kv4[0], k1 = kv4[1];
        float d = q0.x * k0.x + q0.y * k0.y + q0.z * k0.z + q0.w * k0.w
                + q1.x * k1.x + q1.y * k1.y + q1.z * k1.z + q1.w * k1.w;
        d += __shfl_xor(d, 1);
        d += __shfl_xor(d, 2);
        d += __shfl_xor(d, 4);
        d += __shfl_xor(d, 8);       // all 16 lanes of the group hold the dot
        float s = d * 0.08838834764831845f;   // 1/sqrt(128)
        float mn = fmaxf(m, s);
        float corr = __expf(m - mn);          // exp(-inf)=0 on first iter
        float wgt  = __expf(s - mn);
        const float* vp = (p == pos) ? (xv + h * D)
                                     : (cache_v + ((size_t)p * H + h) * D);
        const float4* vv4 = reinterpret_cast<const float4*>(vp + gl * 8);
        float4 v0 = vv4[0], v1 = vv4[1];
        l = l * corr + wgt;
        acc0.x = fmaf(wgt, v0.x, acc0.x * corr);
        acc0.y = fmaf(wgt, v0.y, acc0.y * corr);
        acc0.z = fmaf(wgt, v0.z, acc0.z * corr);
        acc0.w = fmaf(wgt, v0.w, acc0.w * corr);
        acc1.x = fmaf(wgt, v1.x, acc1.x * corr);
        acc1.y = fmaf(wgt, v1.y, acc1.y * corr);
        acc1.z = fmaf(wgt, v1.z, acc1.z * corr);
        acc1.w = fmaf(wgt, v1.w, acc1.w * corr);
        m = mn;
    }

    // combine the 4 groups inside the block
    if (gl == 0) { lds_m[g] = m; lds_l[g] = l; }
    *reinterpret_cast<float4*>(&lds_acc[g][gl * 8])     = acc0;
    *reinterpret_cast<float4*>(&lds_acc[g][gl * 8 + 4]) = acc1;
    __syncthreads();
    float M = fmaxf(fmaxf(lds_m[0], lds_m[1]), fmaxf(lds_m[2], lds_m[3]));
    float w0 = __expf(lds_m[0] - M);
    float w1 = __expf(lds_m[1] - M);
    float w2 = __expf(lds_m[2] - M);
    float w3 = __expf(lds_m[3] - M);
    float L  = w0 * lds_l[0] + w1 * lds_l[1] + w2 * lds_l[2] + w3 * lds_l[3];
    int d0 = 2 * lane;
    float s0 = w0 * lds_acc[0][d0]     + w1 * lds_acc[1][d0]
             + w2 * lds_acc[2][d0]     + w3 * lds_acc[3][d0];
    float s1 = w0 * lds_acc[0][d0 + 1] + w1 * lds_acc[1][d0 + 1]
             + w2 * lds_acc[2][d0 + 1] + w3 * lds_acc[3][d0 + 1];
    if (lane == 0) { pp[0] = M; pp[1] = L; }
    reinterpret_cast<float2*>(pp + 2)[lane] = make_float2(s0, s1);
}

// ---------------- combine partials per head ----------------
__global__ void attn_combine(const float* __restrict__ partials, float* __restrict__ out_attn) {
    int h = blockIdx.x;
    int lane = threadIdx.x;          // 64 lanes, dims 2*lane, 2*lane+1
    float m = -INFINITY;
    for (int c = 0; c < NCHUNK; ++c)
        m = fmaxf(m, partials[(size_t)(h * NCHUNK + c) * PART_STRIDE]);
    float L = 0.f, a0 = 0.f, a1 = 0.f;
    for (int c = 0; c < NCHUNK; ++c) {
        const float* pp = partials + (size_t)(h * NCHUNK + c) * PART_STRIDE;
        float w = __expf(pp[0] - m);      // exp(-inf - m) = 0 for empty chunks
        L += pp[1] * w;
        float2 a = reinterpret_cast<const float2*>(pp + 2)[lane];
        a0 += w * a.x;
        a1 += w * a.y;
    }
    float inv = 1.f / L;
    out_attn[h * D + 2 * lane]     = a0 * inv;
    out_attn[h * D + 2 * lane + 1] = a1 * inv;
}

extern "C" void kernel_launch(void* const* d_in, const int* in_sizes, int n_in,
                              void* d_out, int out_size, void* d_ws, size_t ws_size,
                              hipStream_t stream) {
    const float* x       = (const float*)d_in[0];
    const float* wq      = (const float*)d_in[1];
    const float* wk      = (const float*)d_in[2];
    const float* wv      = (const float*)d_in[3];
    const float* wo      = (const float*)d_in[4];
    const float* cache_k = (const float*)d_in[5];
    const float* cache_v = (const float*)d_in[6];
    const int*   pos     = (const int*)d_in[7];

    float* ws       = (float*)d_ws;
    float* xq       = ws;                 // 4096
    float* xk       = ws + DIM;           // 4096
    float* xv       = ws + 2 * DIM;       // 4096
    float* partials = ws + 3 * DIM;       // 32*64*130
    float* out_attn = partials + H * NCHUNK * PART_STRIDE;  // 4096
    float* out      = (float*)d_out;

    matvec_qkv<<<3 * DIM / 4, 256, 0, stream>>>(wq, wk, wv, x, ws);
    rope_qk<<<16, 256, 0, stream>>>(xq, xk, pos);
    attn_partial<<<dim3(H, NCHUNK), 64, 0, stream>>>(cache_k, cache_v, xq, xk, xv, pos, partials);
    attn_combine<<<H, 64, 0, stream>>>(partials, out_attn);
    matvec_o<<<DIM / 4, 256, 0, stream>>>(wo, out_attn, out);
}